// Round 1
// baseline (679.558 us; speedup 1.0000x reference)
//
#include <hip/hip_runtime.h>
#include <stdint.h>

// out[n] = features[n] @ W[inds[n]] + b[inds[n]],  N=1M, D=64, E=8, fp32.
//
// Design: block = 512 threads = 8 waves, wave w owns expert w.
//  - lane j of wave w holds column j of W[w] in 64 VGPRs (loaded once).
//  - each wave scans the block's token chunk: 1 coalesced inds load + __ballot
//    per 64 tokens -> 64-bit match mask, walked with scalar bit ops (uniform).
//  - per matching token: feature row (256 B, wave-uniform address) loaded into
//    64 SGPRs via s_load_dwordx16 (inline asm; compiler won't scalarize global
//    loads). Inner loop = 64 v_fmac_f32 with SGPR src — no shuffles/bpermute
//    (LDS pipe at ~5.8cyc/op would cost ~600us), no per-token W traffic.
//  - SMEM returns can be out-of-order -> only s_waitcnt lgkmcnt(0) is safe;
//    single wait per token, latency hidden by ~6 waves/SIMD occupancy.

typedef float v16f __attribute__((ext_vector_type(16)));

constexpr int D = 64;
constexpr int CHUNK = 512;   // tokens per block; N=1048576 -> grid=2048

__global__ __launch_bounds__(512, 4)
void moe_split_kernel(const float* __restrict__ features,
                      const int* __restrict__ inds,
                      const float* __restrict__ W,
                      const float* __restrict__ b,
                      float* __restrict__ out, int N) {
    const int w    = threadIdx.x >> 6;   // wave id == expert id
    const int lane = threadIdx.x & 63;   // output column j

    // W[w][k][lane] for k=0..63 -> 64 VGPRs (coalesced 256B loads, L2/L3-hot)
    float wreg[D];
    const float* Wp = W + (size_t)w * D * D + lane;
    #pragma unroll
    for (int k = 0; k < D; ++k) wreg[k] = Wp[k * D];
    const float breg = b[w * D + lane];

    const int base = blockIdx.x * CHUNK;
    const int end  = min(base + CHUNK, N);

    for (int nb = base; nb < end; nb += 64) {
        const int t  = nb + lane;
        const int iv = (t < N) ? inds[t] : -1;
        unsigned long long mask = __ballot(iv == w);
        while (mask) {
            const int i = __builtin_ctzll(mask);
            mask &= mask - 1;
            const int n = nb + i;                       // wave-uniform
            const float* fp = features + (size_t)n * D; // uniform -> SGPR pair

            v16f x0, x1, x2, x3;
            asm volatile(
                "s_load_dwordx16 %0, %4, 0x0\n\t"
                "s_load_dwordx16 %1, %4, 0x40\n\t"
                "s_load_dwordx16 %2, %4, 0x80\n\t"
                "s_load_dwordx16 %3, %4, 0xc0\n\t"
                "s_waitcnt lgkmcnt(0)"
                : "=&s"(x0), "=&s"(x1), "=&s"(x2), "=&s"(x3)
                : "s"(fp));

            float acc0 = breg, acc1 = 0.0f;   // 2 chains to cover fma latency
            #pragma unroll
            for (int k = 0; k < 16; ++k) {
                acc0 = __builtin_fmaf(x0[k], wreg[k],      acc0);
                acc1 = __builtin_fmaf(x1[k], wreg[16 + k], acc1);
            }
            #pragma unroll
            for (int k = 0; k < 16; ++k) {
                acc0 = __builtin_fmaf(x2[k], wreg[32 + k], acc0);
                acc1 = __builtin_fmaf(x3[k], wreg[48 + k], acc1);
            }
            out[(size_t)n * D + lane] = acc0 + acc1;    // coalesced 256B store
        }
    }
}

extern "C" void kernel_launch(void* const* d_in, const int* in_sizes, int n_in,
                              void* d_out, int out_size, void* d_ws, size_t ws_size,
                              hipStream_t stream) {
    const float* features = (const float*)d_in[0];
    const int*   inds     = (const int*)d_in[1];
    const float* W        = (const float*)d_in[2];
    const float* b        = (const float*)d_in[3];
    float*       out      = (float*)d_out;

    const int N = in_sizes[0] / D;       // 1048576
    const int grid = (N + CHUNK - 1) / CHUNK;
    moe_split_kernel<<<grid, 512, 0, stream>>>(features, inds, W, b, out, N);
}